// Round 14
// baseline (264.172 us; speedup 1.0000x reference)
//
#include <hip/hip_runtime.h>

typedef __attribute__((ext_vector_type(8))) short bf16x8;
typedef __attribute__((ext_vector_type(4))) float f32x4;
typedef __attribute__((ext_vector_type(8))) unsigned short ushort8;
typedef __attribute__((ext_vector_type(4))) unsigned short ushort4v;
typedef __attribute__((ext_vector_type(4))) float float4v;
typedef __attribute__((ext_vector_type(2))) unsigned int uint2v;
typedef __attribute__((ext_vector_type(4))) unsigned int uint4v;

#define TGT 256
#define BSZ 64
#define EMB 1024
#define NH 16
#define HD 64
#define PP 16

__device__ __forceinline__ float b2f(unsigned short u) {
  return __builtin_bit_cast(float, ((unsigned int)u) << 16);
}
__device__ __forceinline__ unsigned short f2b(float f) {
  unsigned int u = __builtin_bit_cast(unsigned int, f);
  u += 0x7fffu + ((u >> 16) & 1u);  // RNE; no NaNs in this workload
  return (unsigned short)(u >> 16);
}
__device__ __forceinline__ unsigned int pack2(float lo, float hi) {
  return (unsigned int)f2b(lo) | ((unsigned int)f2b(hi) << 16);
}
__device__ __forceinline__ f32x4 mfma16(bf16x8 a, bf16x8 b, f32x4 c) {
  return __builtin_amdgcn_mfma_f32_16x16x32_bf16(a, b, c, 0, 0, 0);
}
// async global->LDS, 16B per lane; LDS dest is wave-uniform base + lane*16
__device__ __forceinline__ void gl_lds16(const unsigned short* g, unsigned short* l) {
  __builtin_amdgcn_global_load_lds(
      (const __attribute__((address_space(1))) unsigned int*)g,
      (__attribute__((address_space(3))) unsigned int*)l, 16, 0, 0);
}

// ---------------------------------------------------------------------------
// Gate: g1[b] = softmax((feat[b]@gw.T + gb + noise[b]) / 3)[1]
// ---------------------------------------------------------------------------
__global__ __launch_bounds__(64) void gate_kernel(
    const float* __restrict__ feat, const float* __restrict__ gw,
    const float* __restrict__ gb, const float* __restrict__ noise,
    float* __restrict__ g1) {
  const int b = blockIdx.x, lane = threadIdx.x;
  float a0 = 0.f, a1 = 0.f;
  for (int i = lane; i < 512; i += 64) {
    float f = feat[b * 512 + i];
    a0 += f * gw[i];
    a1 += f * gw[512 + i];
  }
#pragma unroll
  for (int off = 32; off >= 1; off >>= 1) {
    a0 += __shfl_xor(a0, off);
    a1 += __shfl_xor(a1, off);
  }
  if (lane == 0) {
    float l0 = (a0 + gb[0] + noise[b * 2 + 0]) * (1.0f / 3.0f);
    float l1 = (a1 + gb[1] + noise[b * 2 + 1]) * (1.0f / 3.0f);
    float mm = fmaxf(l0, l1);
    float e0 = __expf(l0 - mm), e1 = __expf(l1 - mm);
    g1[b] = e1 / (e0 + e1);
  }
}

// ---------------------------------------------------------------------------
// f32 -> bf16 cast, 8 elems/thread, grid-stride (weights only)
// ---------------------------------------------------------------------------
__global__ __launch_bounds__(256) void cast_bf16_kernel(
    const float* __restrict__ in, unsigned short* __restrict__ out, int n8) {
  int i = blockIdx.x * blockDim.x + threadIdx.x;
  const int stride = gridDim.x * blockDim.x;
  for (; i < n8; i += stride) {
    const float4v* p = (const float4v*)(in + (size_t)i * 8);
    float4v v0 = p[0], v1 = p[1];
    ushort8 o = {f2b(v0[0]), f2b(v0[1]), f2b(v0[2]), f2b(v0[3]),
                 f2b(v1[0]), f2b(v1[1]), f2b(v1[2]), f2b(v1[3])};
    *(ushort8*)(out + (size_t)i * 8) = o;
  }
}

// ---------------------------------------------------------------------------
// Shared GEMM geometry: 256x256 tile, 8 waves (2Mx4N, each 128x64), BK=32,
// K=1024 -> 32 steps. SINGLE-BARRIER K-step (R14): all mid-step barriers of
// the old 8-phase skeleton removed -- frag reads touch only data published
// by the PREVIOUS step-end barrier, and every ring-slot overwrite (B 4-ring
// slot (s+3)&3=(s-1)&3, A 2-ring slot (s+1)&1=(s-1)&1) is separated from
// its last reader by that same barrier (all waves pass it before any wave
// issues step-s stores). R11-R13 counters showed 4 barriers/step x wave
// skew was the dominant per-step cost (no pipe >21% busy, ~4650 cyc/step
// vs ~900 cyc of actual work).
// STEP_WAIT: vmcnt backstop + lgkmcnt(0) publish + one barrier.
// ---------------------------------------------------------------------------
#define STEP_WAIT(cntstr)                                \
  asm volatile("s_waitcnt " cntstr ::: "memory");        \
  __builtin_amdgcn_sched_barrier(0);                     \
  __builtin_amdgcn_s_barrier();

// ---------------------------------------------------------------------------
// proj3: ONE dispatch for all three projections (grid 256 x 3; blockIdx.y
// selects q/k/v). C_bf16_headblocked = A_f32 @ W^T + bias.
// A: f32 reg-staged lead-2 ring-2 (R11-proven anchor: compiler-exact vmcnt
// before the f2b pack completes A(s+1) and, oldest-first, B(s+1)); manual
// vmcnt(8) backstop = steady outstanding {B(s+2),A(s+2),B(s+3)} = 2+4+2.
// B: gl_lds lead-3 ring-4 (R4-proven). Rolled 4-step groups keep the reg
// ring literal-indexed. qscale multiplies by 1.0f for k/v (bit-exact).
// ---------------------------------------------------------------------------
#define P3_ISSUE(t, P)                                   \
  {                                                      \
    const float* _p = a32p + (size_t)(t) * 32;           \
    ar[P][0] = *(const float4v*)_p;                      \
    ar[P][1] = *(const float4v*)(_p + 4);                \
    ar[P][2] = *(const float4v*)(_p + 131072);           \
    ar[P][3] = *(const float4v*)(_p + 131072 + 4);       \
  }
#define P3_WRITE(P)                                                     \
  {                                                                     \
    float4v* v = ar[P];                                                 \
    uint4v h0 = {pack2(v[0][0], v[0][1]), pack2(v[0][2], v[0][3]),      \
                 pack2(v[1][0], v[1][1]), pack2(v[1][2], v[1][3])};     \
    uint4v h1 = {pack2(v[2][0], v[2][1]), pack2(v[2][2], v[2][3]),      \
                 pack2(v[3][0], v[3][1]), pack2(v[3][2], v[3][3])};     \
    unsigned short* d = &As[P][swA];                                    \
    *(uint4v*)d = h0;                                                   \
    *(uint4v*)(d + 4096) = h1;                                          \
  }
#define B_STAGE_SLOT(s, SL)                              \
  {                                                      \
    int k0s = (s) * 32;                                  \
    unsigned short* d = &Bs[SL][wl];                     \
    gl_lds16(b0p + k0s, d);                              \
    gl_lds16(b1p + k0s, d + 4096);                       \
  }
#define P3_STEP(s, PAR, BS, DO_IA, DO_SB, DO_W)                       \
  {                                                                   \
    const unsigned short* Ab = &As[PAR][0];                           \
    const unsigned short* Bb = &Bs[BS][0];                            \
    bf16x8 af[8], bfr[4];                                             \
    _Pragma("unroll") for (int mi = 0; mi < 8; ++mi)                  \
        af[mi] = *(const bf16x8*)&Ab[aoff + mi * 512];                \
    _Pragma("unroll") for (int ni = 0; ni < 4; ++ni)                  \
        bfr[ni] = *(const bf16x8*)&Bb[boff + ni * 512];               \
    if (DO_IA) P3_ISSUE((s) + 2, PAR);                                \
    if (DO_SB) B_STAGE_SLOT((s) + 3, ((BS) + 3) & 3);                 \
    __builtin_amdgcn_s_setprio(1);                                    \
    _Pragma("unroll") for (int mi = 0; mi < 8; ++mi)                  \
      _Pragma("unroll") for (int ni = 0; ni < 4; ++ni)                \
        acc[mi][ni] = mfma16(af[mi], bfr[ni], acc[mi][ni]);           \
    __builtin_amdgcn_s_setprio(0);                                    \
    if (DO_W) P3_WRITE((PAR) ^ 1); /* writes A(s+1) */                \
  }

__global__ __launch_bounds__(512, 2) void proj3_kernel(
    const float* __restrict__ q, const float* __restrict__ kk,
    const float* __restrict__ vv, const unsigned short* __restrict__ W3,
    const float* __restrict__ bias3, unsigned short* __restrict__ C3) {
  constexpr int K = 1024;
  __shared__ __attribute__((aligned(16))) unsigned short As[2][8192];  // 32 KB
  __shared__ __attribute__((aligned(16))) unsigned short Bs[4][8192];  // 64 KB
  const int pj = blockIdx.y;
  const float* A = (pj == 0) ? q : ((pj == 1) ? kk : vv);
  const unsigned short* W = W3 + (size_t)pj * 1024 * 1024;
  const float* bias = bias3 + pj * 1024;
  unsigned short* Cv = C3 + (size_t)pj * 16384 * 1024;
  const float qsc = (pj == 0) ? 0.125f : 1.0f;  // *1.0f is bit-exact

  const int tid = threadIdx.x;
  const int wv = tid >> 6, lane = tid & 63;
  const int l15 = lane & 15, kg = lane >> 4;
  const int bid = blockIdx.x;
  const int cpx = gridDim.x >> 3;
  const int wg = (bid & 7) * cpx + (bid >> 3);
  const int m0 = (wg >> 2) * 256, n0 = (wg & 3) * 256;
  const int wmL = (wv >> 2) * 128, wnL = (wv & 3) * 64;

  const int sr = wv * 16 + (lane >> 2);                      // row in 128-half
  const int sc = ((lane & 3) * 8) ^ (((sr >> 1) & 3) << 3);  // pre-swizzled col
  const float* a32p = A + (size_t)(m0 + sr) * K + (lane & 3) * 8;
  const int swA = sr * 32 + (((lane & 3) ^ ((sr >> 1) & 3)) << 3);
  float4v ar[2][4];  // lead-2 reg ring (literal-indexed)
  const unsigned short* b0p = W + (size_t)(n0 + sr) * K + sc;
  const unsigned short* b1p = b0p + (size_t)128 * K;
  const int wl = wv * 512;

  const int x = ((l15 >> 1) & 3) << 3;
  const int aoff = (wmL + l15) * 32 + ((kg * 8) ^ x);
  const int boff = (wnL + l15) * 32 + ((kg * 8) ^ x);

  f32x4 acc[8][4];
#pragma unroll
  for (int i = 0; i < 8; ++i)
#pragma unroll
    for (int j = 0; j < 4; ++j) acc[i][j] = (f32x4){0.f, 0.f, 0.f, 0.f};

  // Prologue (R11-proven counting): A(0),B(0),A(1),B(1),B(2); write A(0).
  // Compiler wait drains A(0); vmcnt(8) completes B(0) (leaves A1,B1,B2=8).
  P3_ISSUE(0, 0); B_STAGE_SLOT(0, 0); P3_ISSUE(1, 1); B_STAGE_SLOT(1, 1);
  B_STAGE_SLOT(2, 2);
  P3_WRITE(0);
  STEP_WAIT("vmcnt(8) lgkmcnt(0)")

#pragma unroll 1
  for (int sb = 0; sb < 28; sb += 4) {
    P3_STEP(sb + 0, 0, 0, 1, 1, 1);
    STEP_WAIT("vmcnt(8) lgkmcnt(0)")
    P3_STEP(sb + 1, 1, 1, 1, 1, 1);
    STEP_WAIT("vmcnt(8) lgkmcnt(0)")
    P3_STEP(sb + 2, 0, 2, 1, 1, 1);
    STEP_WAIT("vmcnt(8) lgkmcnt(0)")
    P3_STEP(sb + 3, 1, 3, 1, 1, 1);
    STEP_WAIT("vmcnt(8) lgkmcnt(0)")
  }
  // Tail s=28..31 (audited R13 counting)
  P3_STEP(28, 0, 0, 1, 1, 1);   // issues A(30), B(31); writes A(29)
  STEP_WAIT("vmcnt(8) lgkmcnt(0)")
  P3_STEP(29, 1, 1, 1, 0, 1);   // issues A(31); writes A(30)
  STEP_WAIT("vmcnt(8) lgkmcnt(0)")
  P3_STEP(30, 0, 2, 0, 0, 1);   // writes A(31); compiler wait drains all
  STEP_WAIT("vmcnt(0) lgkmcnt(0)")
  P3_STEP(31, 1, 3, 0, 0, 0);

#pragma unroll
  for (int mi = 0; mi < 8; ++mi) {
#pragma unroll
    for (int ni = 0; ni < 4; ++ni) {
      int col = n0 + wnL + ni * 16 + l15;
      float bcol = bias[col];
#pragma unroll
      for (int r = 0; r < 4; ++r) {
        int row = m0 + wmL + mi * 16 + kg * 4 + r;
        float v = (acc[mi][ni][r] + bcol) * qsc;
        // head-blocked store: [(b*16+h)][t][d]
        int t = row >> 6, bb = row & 63, hh = col >> 6, dd = col & 63;
        Cv[(size_t)((bb * 16 + hh) * 256 + t) * 64 + dd] = f2b(v);
      }
    }
  }
}

// ---------------------------------------------------------------------------
// gemm256o: out-projection. C_f32[16384,1024] = A_bf16_headblocked @ W^T + b.
// Single-barrier step; A+B both gl_lds lead-3 ring-4 (R4-proven counting:
// steady vmcnt(8) = stages for s+2,s+3; tails 4/0).
// ---------------------------------------------------------------------------
#define O_AOFF(s) (((s) >> 1) * 16384 + ((s)&1) * 32)
#define O_STAGE_A(s)                                     \
  {                                                      \
    const unsigned short* _ap = abf + O_AOFF(s);         \
    unsigned short* d = &As[(s) & 3][wl];                \
    gl_lds16(_ap, d);                                    \
    gl_lds16(_ap + 128, d + 4096);                       \
  }
#define O_STAGE_B(s)                                     \
  {                                                      \
    int k0s = (s) * 32;                                  \
    unsigned short* d = &Bs[(s) & 3][wl];                \
    gl_lds16(b0p + k0s, d);                              \
    gl_lds16(b1p + k0s, d + 4096);                       \
  }
#define O_STEP(s, DO_STAGE)                                           \
  {                                                                   \
    const unsigned short* Ab = &As[(s) & 3][0];                       \
    const unsigned short* Bb = &Bs[(s) & 3][0];                       \
    bf16x8 af[8], bfr[4];                                             \
    _Pragma("unroll") for (int mi = 0; mi < 8; ++mi)                  \
        af[mi] = *(const bf16x8*)&Ab[aoff + mi * 512];                \
    _Pragma("unroll") for (int ni = 0; ni < 4; ++ni)                  \
        bfr[ni] = *(const bf16x8*)&Bb[boff + ni * 512];               \
    if (DO_STAGE) {                                                   \
      O_STAGE_A((s) + 3);                                             \
      O_STAGE_B((s) + 3);                                             \
    }                                                                 \
    __builtin_amdgcn_s_setprio(1);                                    \
    _Pragma("unroll") for (int mi = 0; mi < 8; ++mi)                  \
      _Pragma("unroll") for (int ni = 0; ni < 4; ++ni)                \
        acc[mi][ni] = mfma16(af[mi], bfr[ni], acc[mi][ni]);           \
    __builtin_amdgcn_s_setprio(0);                                    \
  }

__global__ __launch_bounds__(512, 2) void gemm256o_kernel(
    const unsigned short* __restrict__ A, const unsigned short* __restrict__ W,
    const float* __restrict__ bias, float* __restrict__ Cv) {
  constexpr int K = 1024, N = 1024;
  __shared__ __attribute__((aligned(16))) unsigned short As[4][8192];  // 64 KB
  __shared__ __attribute__((aligned(16))) unsigned short Bs[4][8192];  // 64 KB
  const int tid = threadIdx.x;
  const int wv = tid >> 6, lane = tid & 63;
  const int l15 = lane & 15, kg = lane >> 4;
  const int bid = blockIdx.x;
  const int cpx = gridDim.x >> 3;
  const int wg = (bid & 7) * cpx + (bid >> 3);
  const int m0 = (wg >> 2) * 256, n0 = (wg & 3) * 256;
  const int wmL = (wv >> 2) * 128, wnL = (wv & 3) * 64;

  const int sr = wv * 16 + (lane >> 2);
  const int sc = ((lane & 3) * 8) ^ (((sr >> 1) & 3) << 3);
  const int srg = m0 + sr;
  const unsigned short* abf =
      A + (size_t)(srg & 63) * 262144 + (srg >> 6) * 64 + sc;  // head-blocked
  const unsigned short* b0p = W + (size_t)(n0 + sr) * K + sc;
  const unsigned short* b1p = b0p + (size_t)128 * K;
  const int wl = wv * 512;

  const int x = ((l15 >> 1) & 3) << 3;
  const int aoff = (wmL + l15) * 32 + ((kg * 8) ^ x);
  const int boff = (wnL + l15) * 32 + ((kg * 8) ^ x);

  f32x4 acc[8][4];
#pragma unroll
  for (int i = 0; i < 8; ++i)
#pragma unroll
    for (int j = 0; j < 4; ++j) acc[i][j] = (f32x4){0.f, 0.f, 0.f, 0.f};

  O_STAGE_A(0); O_STAGE_B(0); O_STAGE_A(1); O_STAGE_B(1); O_STAGE_A(2); O_STAGE_B(2);
  STEP_WAIT("vmcnt(8)")

  for (int s = 0; s < 29; ++s) {
    O_STEP(s, 1);
    STEP_WAIT("vmcnt(8)")
  }
  O_STEP(29, 0);
  STEP_WAIT("vmcnt(4)")
  O_STEP(30, 0);
  STEP_WAIT("vmcnt(0)")
  O_STEP(31, 0);

#pragma unroll
  for (int mi = 0; mi < 8; ++mi) {
#pragma unroll
    for (int ni = 0; ni < 4; ++ni) {
      int col = n0 + wnL + ni * 16 + l15;
      float bcol = bias[col];
#pragma unroll
      for (int r = 0; r < 4; ++r) {
        int row = m0 + wmL + mi * 16 + kg * 4 + r;
        Cv[(size_t)row * N + col] = acc[mi][ni][r] + bcol;
      }
    }
  }
}

// ---------------------------------------------------------------------------
// MFMA attention per (b,h) — EXACT R4-proven kernel.
// q/k/v/comb HEAD-BLOCKED [(b*16+h)][t][d]; 8 waves x 32 t-rows,
// strip-merged; natural-log softmax via __expf; pack2/f2b packing;
// T13 defer-rescale; V^T gran swizzle.
// combined = attn + g1[t>>2]*bw[b]*attn_pre (uses g0+g1==1).
// Q pre-scaled by 0.125 in the q-projection.
// ---------------------------------------------------------------------------
__global__ __launch_bounds__(512) void attn_kernel(
    const unsigned short* __restrict__ qb, const unsigned short* __restrict__ kb,
    const unsigned short* __restrict__ vb, const float* __restrict__ prefix,
    const float* __restrict__ bw, const float* __restrict__ g1,
    unsigned short* __restrict__ comb) {
  const int b = blockIdx.x, h = blockIdx.y;
  __shared__ __attribute__((aligned(16))) unsigned short Kl[256][64];    // 32 KB, chunk-XOR
  __shared__ __attribute__((aligned(16))) unsigned short Vt[64 * 256];   // 32 KB, V^T swizzled
  __shared__ __attribute__((aligned(16))) unsigned short PKl[16][64];    // 2 KB, chunk-XOR
  __shared__ __attribute__((aligned(16))) unsigned short PVt[64][32];    // 4 KB
  __shared__ __attribute__((aligned(16))) unsigned short Plds[8][16][40];// 10 KB, per-wave P
  unsigned short* Cb = &Kl[0][0];  // output bounce overlays Kl
  const int tid = threadIdx.x;
  const int wv = tid >> 6, lane = tid & 63;
  const size_t slab = (size_t)(b * NH + h) * 16384;

  // ---- staging (coalesced slab reads) ----
#pragma unroll
  for (int it = 0; it < 4; ++it) {
    int cid = tid + it * 512;
    int j = cid >> 3, c = cid & 7;  // j = s row, c = d-chunk
    gl_lds16(kb + slab + (size_t)j * 64 + ((c ^ (j & 7)) << 3),
             &Kl[0][0] + (size_t)(it * 512 + wv * 64) * 8);
    ushort8 vv = *(const ushort8*)(vb + slab + (size_t)j * 64 + (c << 3));
#pragma unroll
    for (int i = 0; i < 8; ++i) {  // V^T: (d=c*8+i, s=j); gran = (s>>3)^(d&7)^(d>>3)
      int gran = (j >> 3) ^ i ^ c;
      Vt[(c * 8 + i) * 256 + gran * 8 + (j & 7)] = vv[i];
    }
  }
  if (tid < 256) {
    int arr = tid >> 7, cid = tid & 127;
    int sp = cid >> 3, c = cid & 7;
    const float* src = prefix + ((size_t)(b * 2 + arr) * PP + sp) * EMB + h * HD + c * 8;
    float4v v0 = *(const float4v*)src;
    float4v v1 = *(const float4v*)(src + 4);
    if (arr == 0) {
      ushort8 o = {f2b(v0[0]), f2b(v0[1]), f2b(v0[2]), f2b(v0[3]),
                   f2b(v1[0]), f2b(v1[1]), f2b(v1[2]), f2b(v1[3])};
      *(ushort8*)&PKl[sp][((c ^ (sp & 7)) << 3)] = o;
    } else {
#pragma unroll
      for (int i = 0; i < 8; ++i)
        PVt[c * 8 + i][sp] = f2b(i < 4 ? v0[i] : v1[i - 4]);
    }
  } else if (tid < 384) {
    int cid = tid - 256;
    *(ushort8*)&PVt[cid >> 1][16 + (cid & 1) * 8] = (ushort8){0, 0, 0, 0, 0, 0, 0, 0};
  }
  __syncthreads();

  const int l15 = lane & 15, g = lane >> 4;
  const int swl = l15 & 7;
  const float bwb = bw[b];
  unsigned short(&Pw)[16][40] = Plds[wv];

  const int t0 = wv * 32 + l15;  // strip-0 row; strip-1 = t0+16
  const size_t qbase = slab + (size_t)t0 * 64;
  bf16x8 qf[2][2];
  qf[0][0] = *(const bf16x8*)(qb + qbase + g * 8);
  qf[0][1] = *(const bf16x8*)(qb + qbase + 32 + g * 8);
  qf[1][0] = *(const bf16x8*)(qb + qbase + 1024 + g * 8);
  qf[1][1] = *(const bf16x8*)(qb + qbase + 1024 + 32 + g * 8);

  f32x4 O[2][4];
#pragma unroll
  for (int st = 0; st < 2; ++st)
#pragma unroll
    for (int dt = 0; dt < 4; ++dt) O[st][dt] = (f32x4){0.f, 0.f, 0.f, 0.f};
  float m[2] = {-3.0e38f, -3.0e38f}, l[2] = {0.f, 0.f};

#pragma unroll
  for (int ch = 0; ch < 8; ++ch) {  // 32 s per chunk
    const int rA = ch * 32 + l15, rB = rA + 16;
    bf16x8 ka0 = *(const bf16x8*)&Kl[rA][((g ^ swl) << 3)];
    bf16x8 ka1 = *(const bf16x8*)&Kl[rA][(((4 + g) ^ swl) << 3)];
    bf16x8 kb0 = *(const bf16x8*)&Kl[rB][((g ^ swl) << 3)];
    bf16x8 kb1 = *(const bf16x8*)&Kl[rB][(((4 + g) ^ swl) << 3)];
    f32x4 s[2][2];
#pragma unroll
    for (int st = 0; st < 2; ++st) {
      s[st][0] = (f32x4){0.f, 0.f, 0.f, 0.f};
      s[st][1] = (f32x4){0.f, 0.f, 0.f, 0.f};
      s[st][0] = mfma16(ka0, qf[st][0], s[st][0]);
      s[st][0] = mfma16(ka1, qf[st][1], s[st][0]);
      s[st][1] = mfma16(kb0, qf[st][0], s[st][1]);
      s[st][1] = mfma16(kb1, qf[st][1], s[st][1]);
    }
    bf16x8 pf[2];
#pragma unroll
    for (int st = 0; st < 2; ++st) {
      f32x4 sa = s[st][0], sb = s[st][1];
      float mx = fmaxf(fmaxf(fmaxf(sa[0], sa[1]), fmaxf(sa[2], sa[3])),
                       fmaxf(fmaxf(sb[0], sb[1]), fmaxf(sb[2], sb[3])));
      mx = fmaxf(mx, __shfl_xor(mx, 16));
      mx = fmaxf(mx, __shfl_xor(mx, 32));
      // T13 defer-rescale: only rescale when some row grew by > 8
      if (__ballot(mx > m[st] + 8.0f) != 0ull) {
        float mn = fmaxf(m[st], mx);
        float f = __expf(m[st] - mn);
        m[st] = mn;
        l[st] *= f;
#pragma unroll
        for (int dt = 0; dt < 4; ++dt)
#pragma unroll
          for (int r = 0; r < 4; ++r) O[st][dt][r] *= f;
      }
      float pA[4], pB[4];
#pragma unroll
      for (int r = 0; r < 4; ++r) {
        pA[r] = __expf(sa[r] - m[st]);
        pB[r] = __expf(sb[r] - m[st]);
      }
      uint2v wa = {pack2(pA[0], pA[1]), pack2(pA[2], pA[3])};
      uint2v wb2 = {pack2(pB[0], pB[1]), pack2(pB[2], pB[3])};
      *(uint2v*)&Pw[l15][g * 4] = wa;
      *(uint2v*)&Pw[l15][16 + g * 4] = wb2;
      // l accumulates the ROUNDED p so normalization compensates quantization
      float sloc = b2f((unsigned short)(wa[0] & 0xffff)) + b2f((unsigned short)(wa[0] >> 16)) +
                   b2f((unsigned short)(wa[1] & 0xffff)) + b2f((unsigned short)(wa[1] >> 16)) +
                   b2f((unsigned short)(wb2[0] & 0xffff)) + b2f((unsigned short)(wb2[0] >> 16)) +
                   b2f((unsigned short)(wb2[1] & 0xffff)) + b2f((unsigned short)(wb2[1] >> 16));
      l[st] += sloc;
      // read own B-frag before next strip overwrites the tile (in-order DS)
      pf[st] = *(const bf16x8*)&Pw[l15][g * 8];
    }
#pragma unroll
    for (int dt = 0; dt < 4; ++dt) {
      const int drow = dt * 16 + l15;
      const int gran = (ch * 4 + g) ^ (drow & 7) ^ (drow >> 3);
      bf16x8 vf = *(const bf16x8*)&Vt[drow * 256 + gran * 8];
      O[0][dt] = mfma16(vf, pf[0], O[0][dt]);
      O[1][dt] = mfma16(vf, pf[1], O[1][dt]);
    }
  }

#pragma unroll
  for (int st = 0; st < 2; ++st) {
    float lf = l[st];
    lf += __shfl_xor(lf, 16);
    lf += __shfl_xor(lf, 32);
    float inv = 1.0f / lf;
#pragma unroll
    for (int dt = 0; dt < 4; ++dt)
#pragma unroll
      for (int r = 0; r < 4; ++r) O[st][dt][r] *= inv;
  }

  // prefix attention (s=16 zero-padded to 32), scaled by g1*bw/sum
  {
    bf16x8 pk0 = *(const bf16x8*)&PKl[l15][((g ^ swl) << 3)];
    bf16x8 pk1 = *(const bf16x8*)&PKl[l15][(((4 + g) ^ swl) << 3)];
    bf16x8 ppf[2];
#pragma unroll
    for (int st = 0; st < 2; ++st) {
      f32x4 sp4 = (f32x4){0.f, 0.f, 0.f, 0.f};
      sp4 = mfma16(pk0, qf[st][0], sp4);
      sp4 = mfma16(pk1, qf[st][1], sp4);
      float pm = fmaxf(fmaxf(sp4[0], sp4[1]), fmaxf(sp4[2], sp4[3]));
      pm = fmaxf(pm, __shfl_xor(pm, 16));
      pm = fmaxf(pm, __shfl_xor(pm, 32));
      float pe[4], pl = 0.f;
#pragma unroll
      for (int r = 0; r < 4; ++r) {
        pe[r] = __expf(sp4[r] - pm);
        pl += pe[r];
      }
      pl += __shfl_xor(pl, 16);
      pl += __shfl_xor(pl, 32);
      float cpre = g1[(t0 + 16 * st) >> 2] * bwb / pl;
#pragma unroll
      for (int r = 0; r < 4; ++r) pe[r] *= cpre;
      *(uint2v*)&Pw[l15][g * 4] = (uint2v){pack2(pe[0], pe[1]), pack2(pe[2], pe[3])};
      *(uint2v*)&Pw[l15][16 + g * 4] = (uint2v){0u, 0u};
      ppf[st] = *(const bf16x8*)&Pw[l15][g * 8];
    }
#pragma unroll
    for (int dt = 0; dt < 4; ++dt) {
      bf16x8 pvf = *(const bf16x8*)&PVt[dt * 16 + l15][g * 8];
      O[0][dt] = mfma16(pvf, ppf[0], O[0][dt]);
      O[1][dt] = mfma16(pvf, ppf[1], O[1][dt]);
    }
  }

  __syncthreads();  // all waves done reading Kl before bounce overlays it
#pragma unroll
  for (int st = 0; st < 2; ++st) {
    int t = wv * 32 + st * 16 + l15;
#pragma unroll
    for (int dt = 0; dt < 4; ++dt) {
#pragma unroll
      for (int u = 0; u < 2; ++u) {
        unsigned int pw = pack2(O[st][dt][2 * u], O[st][dt][2 * u + 1]);
        int d = dt * 16 + g * 4 + 2 * u;
        *(unsigned int*)&Cb[t * 64 + (((d >> 3) ^ (t & 7)) << 3) + (d & 7)] = pw;
      }
    }
  }
  __syncthreads();
#pragma unroll
  for (int it = 0; it < 4; ++it) {
    int cid = tid + it * 512;
    int j = cid >> 3, c = cid & 7;
    ushort8 row = *(const ushort8*)&Cb[j * 64 + ((c ^ (j & 7)) << 3)];
    *(ushort8*)(comb + slab + (size_t)j * 64 + (c << 3)) = row;
  }
}

// ---------------------------------------------------------------------------
extern "C" void kernel_launch(void* const* d_in, const int* in_sizes, int n_in,
                              void* d_out, int out_size, void* d_ws, size_t ws_size,
                              hipStream_t stream) {
  const float* query = (const float*)d_in[1];
  const float* key = (const float*)d_in[2];
  const float* value = (const float*)d_in[3];
  const float* prefix = (const float*)d_in[4];
  const float* bw = (const float*)d_in[5];
  const float* feat = (const float*)d_in[6];
  const float* noise = (const float*)d_in[7];
  const float* ipw = (const float*)d_in[8];
  const float* ipb = (const float*)d_in[9];
  const float* outw = (const float*)d_in[10];
  const float* outb = (const float*)d_in[11];
  const float* gw = (const float*)d_in[12];
  const float* gb = (const float*)d_in[13];
  float* out = (float*)d_out;

  char* ws = (char*)d_ws;
  const size_t MATB = (size_t)16384 * 1024;  // elements per [16384,1024] matrix
  unsigned short* qb = (unsigned short*)ws;  // q/k/v contiguous: proj3 C-base
  unsigned short* kb = qb + MATB;
  unsigned short* vb = kb + MATB;
  unsigned short* cb = vb + MATB;            // attn output (head-blocked)
  unsigned short* wip = cb + MATB;           // bf16 in_proj_w [3072,1024]
  unsigned short* wo = wip + (size_t)3072 * 1024;  // bf16 out_w [1024,1024]
  float* g1 = (float*)(wo + (size_t)1024 * 1024);

  gate_kernel<<<64, 64, 0, stream>>>(feat, gw, gb, noise, g1);

  // weight casts only (16.8 MB total)
  cast_bf16_kernel<<<1536, 256, 0, stream>>>(ipw, wip, 3072 * 1024 / 8);
  cast_bf16_kernel<<<512, 256, 0, stream>>>(outw, wo, 1024 * 1024 / 8);

  // all three projections in ONE dispatch (blockIdx.y selects q/k/v)
  proj3_kernel<<<dim3(256, 3), 512, 0, stream>>>(query, key, value, wip, ipb, qb);

  attn_kernel<<<dim3(64, 16), 512, 0, stream>>>(qb, kb, vb, prefix, bw, g1, cb);

  // out-projection reads head-blocked bf16 attn output
  gemm256o_kernel<<<256, 512, 0, stream>>>(cb, wo, outb, out);
}